// Round 14
// baseline (265.804 us; speedup 1.0000x reference)
//
#include <hip/hip_runtime.h>
#include <math.h>

#define NEG_SLOPE 0.2f

typedef __attribute__((ext_vector_type(8))) short short8;   // 8 bf16 (4 VGPRs)
typedef __attribute__((ext_vector_type(4))) float f32x4;
typedef __attribute__((ext_vector_type(2))) float f32x2;

// ---------- helpers ----------
__device__ __forceinline__ float lrelu(float v) { return v > 0.f ? v : NEG_SLOPE * v; }
__device__ __forceinline__ float elu(float v) { return v > 0.f ? v : (__expf(v) - 1.f); }
__device__ __forceinline__ unsigned short f2b(float f) {   // fp32 -> bf16 RNE
    unsigned u = __float_as_uint(f);
    return (unsigned short)((u + 0x7FFFu + ((u >> 16) & 1u)) >> 16);
}
__device__ __forceinline__ float blo(unsigned v) { return __uint_as_float(v << 16); }
__device__ __forceinline__ float bhi(unsigned v) { return __uint_as_float(v & 0xFFFF0000u); }
__device__ __forceinline__ unsigned packb(float a, float b) {
    return ((unsigned)f2b(b) << 16) | (unsigned)f2b(a);
}
// fp8 e4m3 (OCP, gfx950 HW converts)
__device__ __forceinline__ unsigned short pack8(float a, float b) {
    return (unsigned short)(__builtin_amdgcn_cvt_pk_fp8_f32(a, b, 0, false) & 0xFFFF);
}
__device__ __forceinline__ f32x2 unpack8(unsigned v) {
    return __builtin_amdgcn_cvt_pk_f32_fp8((int)v, false);
}
__device__ __forceinline__ f32x2 unpack8hi(unsigned v) {
    return __builtin_amdgcn_cvt_pk_f32_fp8((int)v, true);
}
// two f32 -> packed bf16 pair by truncation (exact when inputs came from fp8)
__device__ __forceinline__ unsigned bpack_trunc(f32x2 f) {
    return (__float_as_uint(f.y) & 0xFFFF0000u) | (__float_as_uint(f.x) >> 16);
}
// LDS xor-swizzle: 16B-chunk o within row r
__device__ __forceinline__ int sw(int r, int o) { return (o ^ (r & 7)) << 3; }

// ---------- prep: h1 (bf16 + fp8) + weight transforms + degree count ----------
__global__ void prep_k(const int* __restrict__ x, const int* __restrict__ et,
                       const int* __restrict__ ei,
                       const float* __restrict__ ent_emb, const float* __restrict__ rel_emb,
                       const float* __restrict__ W1, const float* __restrict__ W2,
                       const float* __restrict__ a1s, const float* __restrict__ a1d,
                       unsigned* __restrict__ h1b2, unsigned short* __restrict__ h1q,
                       unsigned short* __restrict__ wsb, unsigned short* __restrict__ W1t,
                       unsigned short* __restrict__ W2t, int* __restrict__ deg,
                       int N, int E) {
    int t = blockIdx.x * blockDim.x + threadIdx.x;
    if (t < N * 64) {            // pair j: cols 2j, 2j+1
        int n = t >> 6, j = t & 63;
        float v0, v1;
        if (j < 32) {
            const float* e = ent_emb + (size_t)x[n] * 64 + 2 * j;
            v0 = e[0]; v1 = e[1];
        } else {
            const float* r = rel_emb + (size_t)et[n] * 64 + 2 * (j - 32);
            v0 = r[0]; v1 = r[1];
        }
        h1b2[t] = packb(v0, v1);
        h1q[t] = pack8(v0, v1);
    }
    if (t < 2048) {  // wsb[hh][k]: hh<8 -> W1.a1s, else W1.a1d
        int hh = t >> 7, k = t & 127, h = hh & 7;
        const float* aw = (hh < 8) ? a1s : a1d;
        const float* wr = W1 + (size_t)k * 512 + h * 64;
        float s_ = 0.f;
#pragma unroll 16
        for (int c = 0; c < 64; c++) s_ += wr[c] * aw[h * 64 + c];
        wsb[t] = f2b(s_);
    }
    if (t < 512 * 128) {  // W1t[n][k] = W1[k][n]
        int n = t >> 7, kk = t & 127;
        W1t[t] = f2b(W1[(size_t)kk * 512 + n]);
    }
    if (t < 64 * 576) {   // W2t[n][k] = W2[k][n]
        int n = t / 576, k = t % 576;
        W2t[t] = f2b(W2[(size_t)k * 64 + n]);
    }
    if (t < E + N) {      // degree (incl self-loop); deg[] zeroed by memset
        int dst = t < E ? ei[E + t] : t - E;
        atomicAdd(&deg[dst], 1);
    }
}

// ---------- attn1 (MFMA): [als|ald][N,16] = h1[N,128] @ wsb[16,128]^T ----------
__global__ __launch_bounds__(256) void attn1_k(const unsigned short* __restrict__ A,
                                               const unsigned short* __restrict__ Bt,
                                               float* __restrict__ als, float* __restrict__ ald,
                                               int M) {
    __shared__ __align__(16) unsigned short As[128 * 128];
    __shared__ __align__(16) unsigned short Bs[16 * 128];
    int tid = threadIdx.x;
    int m0 = blockIdx.x * 128;
    for (int c = tid; c < 2048; c += 256) {
        int r = c >> 4, o = c & 15;
        int gr = m0 + r;
        uint4 v = make_uint4(0u, 0u, 0u, 0u);
        if (gr < M) v = *(const uint4*)(A + (size_t)gr * 128 + o * 8);
        *(uint4*)(As + r * 128 + sw(r, o)) = v;
    }
    if (tid < 256) {
        int r = tid >> 4, o = tid & 15;
        uint4 v = *(const uint4*)(Bt + (size_t)r * 128 + o * 8);
        *(uint4*)(Bs + r * 128 + sw(r, o)) = v;
    }
    __syncthreads();
    int w = tid >> 6, lane = tid & 63;
    int wr = w * 32;
    int m16 = lane & 15, quad = lane >> 4;
    f32x4 acc[2] = {};
#pragma unroll
    for (int kk = 0; kk < 128; kk += 32) {
        int ob = (kk >> 3) + quad;
        short8 b = *(const short8*)(Bs + m16 * 128 + sw(m16, ob));
#pragma unroll
        for (int i = 0; i < 2; i++) {
            int r = wr + i * 16 + m16;
            short8 a = *(const short8*)(As + r * 128 + sw(r, ob));
            acc[i] = __builtin_amdgcn_mfma_f32_16x16x32_bf16(a, b, acc[i], 0, 0, 0);
        }
    }
#pragma unroll
    for (int i = 0; i < 2; i++)
#pragma unroll
        for (int reg = 0; reg < 4; reg++) {
            int row = m0 + wr + i * 16 + quad * 4 + reg;
            if (row < M) {
                if (m16 < 8) als[row * 8 + m16] = acc[i][reg];
                else         ald[row * 8 + (m16 - 8)] = acc[i][reg];
            }
        }
}

// ---------- single-dispatch decoupled-lookback scan: deg -> offs ----------
__global__ __launch_bounds__(256) void scan_k(const int* __restrict__ deg,
                                              int* __restrict__ offs,
                                              int* __restrict__ bstate,
                                              int N, int Etot, int NB) {
    __shared__ int s[256];
    __shared__ int sbase;
    int b = blockIdx.x, t = threadIdx.x;
    int i = b * 256 + t;
    int v = (i < N) ? deg[i] : 0;
    s[t] = v;
    __syncthreads();
    for (int off = 1; off < 256; off <<= 1) {
        int tmp = (t >= off) ? s[t - off] : 0;
        __syncthreads();
        s[t] += tmp;
        __syncthreads();
    }
    int total = s[255];
    if (t == 0) {
        if (b == 0) {
            atomicExch(&bstate[0], (total << 2) | 2);
            sbase = 0;
        } else {
            atomicExch(&bstate[b], (total << 2) | 1);
            int run = 0;
            for (int p = b - 1; p >= 0;) {
                int stv;
                do { stv = atomicAdd(&bstate[p], 0); } while ((stv & 3) == 0);
                run += (stv >> 2);
                if ((stv & 3) == 2) break;
                p--;
            }
            atomicExch(&bstate[b], ((run + total) << 2) | 2);
            sbase = run;
        }
    }
    __syncthreads();
    if (i < N) offs[i] = sbase + s[t] - v;
    if (b == NB - 1 && t == 0) offs[N] = Etot;
}

// ---------- CSR fill (src only) ----------
__global__ void fill_k(const int* __restrict__ ei, int E, int N,
                       const int* __restrict__ offs, int* __restrict__ cursor,
                       int* __restrict__ csr) {
    int e = blockIdx.x * blockDim.x + threadIdx.x;
    if (e >= E + N) return;
    int src = e < E ? ei[e] : e - E;
    int dst = e < E ? ei[E + e] : e - E;
    int pos = offs[dst] + atomicAdd(&cursor[dst], 1);
    csr[pos] = src;
}

// ---------- alpha1: dst-centric per-edge numerators (CSR order, bf16) + inv1 ----------
__global__ __launch_bounds__(256) void alpha1_k(const float* __restrict__ als1,
                                                const float* __restrict__ ald1,
                                                const int* __restrict__ offs,
                                                const int* __restrict__ csr,
                                                unsigned short* __restrict__ ex1b,
                                                float* __restrict__ inv1, int N) {
    int slot = threadIdx.x >> 3, h = threadIdx.x & 7;
    int n = blockIdx.x * 32 + slot;
    if (n >= N) return;
    float dl = ald1[n * 8 + h];
    int p0 = offs[n], p1 = offs[n + 1];
    float ssum = 0.f;
    for (int p = p0; p < p1; p++) {
        int src = csr[p];
        float xv = __expf(lrelu(als1[src * 8 + h] + dl));
        ex1b[(size_t)p * 8 + h] = f2b(xv);
        ssum += xv;
    }
    inv1[n * 8 + h] = 8.f / (ssum + 1e-16f);   // x8 fp8 scale folded in
}

// ---------- aggG: weighted gather-sum; 4-edge unroll; bf16 alphas; G fp8 x8 ----------
__global__ __launch_bounds__(256) void aggG_k(const unsigned short* __restrict__ h1q,
                                              const unsigned short* __restrict__ ex1b,
                                              const float* __restrict__ inv1,
                                              const int* __restrict__ offs,
                                              const int* __restrict__ csr,
                                              unsigned short* __restrict__ Gq,
                                              unsigned short* __restrict__ h2q16, int N) {
    int wv = threadIdx.x >> 6;
    int t = threadIdx.x & 63;
    int n = blockIdx.x * 4 + wv;
    if (n >= N) return;
    int p0 = offs[n], p1 = offs[n + 1];
    float a0[8] = {}, a1[8] = {};
    int p = p0;
    for (; p + 3 < p1; p += 4) {
        int sA = csr[p], sB = csr[p + 1], sC = csr[p + 2], sD = csr[p + 3];
        uint4 eA = *(const uint4*)(ex1b + (size_t)p * 8);
        uint4 eB = *(const uint4*)(ex1b + (size_t)p * 8 + 8);
        uint4 eC = *(const uint4*)(ex1b + (size_t)p * 8 + 16);
        uint4 eD = *(const uint4*)(ex1b + (size_t)p * 8 + 24);
        unsigned hA = h1q[sA * 64 + t];
        unsigned hB = h1q[sB * 64 + t];
        unsigned hC = h1q[sC * 64 + t];
        unsigned hD = h1q[sD * 64 + t];
        f32x2 fA = unpack8(hA), fB = unpack8(hB), fC = unpack8(hC), fD = unpack8(hD);
        float evA[8] = {blo(eA.x), bhi(eA.x), blo(eA.y), bhi(eA.y),
                        blo(eA.z), bhi(eA.z), blo(eA.w), bhi(eA.w)};
        float evB[8] = {blo(eB.x), bhi(eB.x), blo(eB.y), bhi(eB.y),
                        blo(eB.z), bhi(eB.z), blo(eB.w), bhi(eB.w)};
        float evC[8] = {blo(eC.x), bhi(eC.x), blo(eC.y), bhi(eC.y),
                        blo(eC.z), bhi(eC.z), blo(eC.w), bhi(eC.w)};
        float evD[8] = {blo(eD.x), bhi(eD.x), blo(eD.y), bhi(eD.y),
                        blo(eD.z), bhi(eD.z), blo(eD.w), bhi(eD.w)};
#pragma unroll
        for (int h = 0; h < 8; h++) {
            a0[h] += evA[h] * fA.x + evB[h] * fB.x + evC[h] * fC.x + evD[h] * fD.x;
            a1[h] += evA[h] * fA.y + evB[h] * fB.y + evC[h] * fC.y + evD[h] * fD.y;
        }
    }
    for (; p < p1; p++) {
        int sA = csr[p];
        uint4 eA = *(const uint4*)(ex1b + (size_t)p * 8);
        f32x2 fA = unpack8(h1q[sA * 64 + t]);
        float evA[8] = {blo(eA.x), bhi(eA.x), blo(eA.y), bhi(eA.y),
                        blo(eA.z), bhi(eA.z), blo(eA.w), bhi(eA.w)};
#pragma unroll
        for (int h = 0; h < 8; h++) { a0[h] += evA[h] * fA.x; a1[h] += evA[h] * fA.y; }
    }
    float4 i0 = *(const float4*)(inv1 + n * 8);
    float4 i1 = *(const float4*)(inv1 + n * 8 + 4);
    float iv[8] = {i0.x, i0.y, i0.z, i0.w, i1.x, i1.y, i1.z, i1.w};
#pragma unroll
    for (int h = 0; h < 8; h++)
        Gq[(n * 8 + h) * 64 + t] = pack8(a0[h] * iv[h], a1[h] * iv[h]);
    if (t < 32)  // ent tail: h2 fp8 cols 512..575 = h1q fp8 pairs (row stride 576B = 288 u16)
        h2q16[(size_t)n * 288 + 256 + t] = h1q[n * 64 + t];
}

// ---------- gemmG: h2(fp8) = elu((G*8)@W1t * 0.125 + b1); A staged from fp8 ----------
__global__ __launch_bounds__(256) void gemmG_k(const unsigned char* __restrict__ Gq8,
                                               const unsigned short* __restrict__ W1t,
                                               const float* __restrict__ b1,
                                               unsigned char* __restrict__ h2q8, int M) {
    __shared__ __align__(16) unsigned short As[128 * 128];
    __shared__ __align__(16) unsigned short Bs[64 * 128];
    int tid = threadIdx.x;
    int m0 = blockIdx.x * 128, h = blockIdx.y;
    for (int c = tid; c < 1024; c += 256) {
        int r = c >> 3, o = c & 7;     // o: 16-fp8 chunk
        int gr = m0 + r;
        uint4 v = make_uint4(0u, 0u, 0u, 0u);
        if (gr < M) v = *(const uint4*)(Gq8 + ((size_t)gr * 8 + h) * 128 + o * 16);
        uint4 w0, w1;
        w0.x = bpack_trunc(unpack8(v.x));   w0.y = bpack_trunc(unpack8hi(v.x));
        w0.z = bpack_trunc(unpack8(v.y));   w0.w = bpack_trunc(unpack8hi(v.y));
        w1.x = bpack_trunc(unpack8(v.z));   w1.y = bpack_trunc(unpack8hi(v.z));
        w1.z = bpack_trunc(unpack8(v.w));   w1.w = bpack_trunc(unpack8hi(v.w));
        *(uint4*)(As + r * 128 + sw(r, 2 * o)) = w0;
        *(uint4*)(As + r * 128 + sw(r, 2 * o + 1)) = w1;
    }
    for (int c = tid; c < 1024; c += 256) {
        int r = c >> 4, o = c & 15;
        uint4 v = *(const uint4*)(W1t + (size_t)(h * 64 + r) * 128 + o * 8);
        *(uint4*)(Bs + r * 128 + sw(r, o)) = v;
    }
    __syncthreads();
    int w = tid >> 6, lane = tid & 63;
    int wr = w * 32;
    int m16 = lane & 15, quad = lane >> 4;
    f32x4 acc[2][4] = {};
#pragma unroll
    for (int kk = 0; kk < 128; kk += 32) {
        int ob = (kk >> 3) + quad;
        short8 b[4];
#pragma unroll
        for (int j = 0; j < 4; j++) {
            int r = j * 16 + m16;
            b[j] = *(const short8*)(Bs + r * 128 + sw(r, ob));
        }
#pragma unroll
        for (int i = 0; i < 2; i++) {
            int r = wr + i * 16 + m16;
            short8 a = *(const short8*)(As + r * 128 + sw(r, ob));
#pragma unroll
            for (int j = 0; j < 4; j++)
                acc[i][j] = __builtin_amdgcn_mfma_f32_16x16x32_bf16(a, b[j], acc[i][j], 0, 0, 0);
        }
    }
#pragma unroll
    for (int i = 0; i < 2; i++)
#pragma unroll
        for (int j = 0; j < 4; j++)
#pragma unroll
            for (int reg = 0; reg < 4; reg++) {
                int row = m0 + wr + i * 16 + quad * 4 + reg;
                int col = h * 64 + j * 16 + m16;
                if (row < M) {
                    float v = elu(acc[i][j][reg] * 0.125f + b1[col]);
                    h2q8[(size_t)row * 576 + col] =
                        (unsigned char)(__builtin_amdgcn_cvt_pk_fp8_f32(v, 0.f, 0, false) & 0xFF);
                }
            }
}

// ---------- gemm2 (+fused attn2): hl2q(fp8) = h2(fp8) @ W2t^T ----------
__global__ __launch_bounds__(256) void gemm2_k(const unsigned char* __restrict__ Aq8,
                                               const unsigned short* __restrict__ Bt,
                                               const float* __restrict__ a2s,
                                               const float* __restrict__ a2d,
                                               unsigned char* __restrict__ hl2q,
                                               float* __restrict__ als2,
                                               float* __restrict__ ald2, int M) {
    __shared__ __align__(16) unsigned short As[64 * 64];
    __shared__ __align__(16) unsigned short Bs[64 * 64];
    int tid = threadIdx.x;
    int m0 = blockIdx.x * 64;
    int w = tid >> 6, lane = tid & 63;
    int m16 = lane & 15, quad = lane >> 4;
    f32x4 acc[4] = {};
    for (int k0 = 0; k0 < 576; k0 += 64) {
        __syncthreads();
        {   // A: 64 rows x 64 fp8 -> bf16 (exact); exactly 256 chunks
            int r = tid >> 2, o = tid & 3;   // o: 16-fp8 chunk
            int gr = m0 + r;
            uint4 v = make_uint4(0u, 0u, 0u, 0u);
            if (gr < M) v = *(const uint4*)(Aq8 + (size_t)gr * 576 + k0 + o * 16);
            uint4 w0, w1;
            w0.x = bpack_trunc(unpack8(v.x));   w0.y = bpack_trunc(unpack8hi(v.x));
            w0.z = bpack_trunc(unpack8(v.y));   w0.w = bpack_trunc(unpack8hi(v.y));
            w1.x = bpack_trunc(unpack8(v.z));   w1.y = bpack_trunc(unpack8hi(v.z));
            w1.z = bpack_trunc(unpack8(v.w));   w1.w = bpack_trunc(unpack8hi(v.w));
            *(uint4*)(As + r * 64 + sw(r, 2 * o)) = w0;
            *(uint4*)(As + r * 64 + sw(r, 2 * o + 1)) = w1;
        }
        for (int c = tid; c < 512; c += 256) {
            int r = c >> 3, o = c & 7;
            uint4 v = *(const uint4*)(Bt + (size_t)r * 576 + k0 + o * 8);
            *(uint4*)(Bs + r * 64 + sw(r, o)) = v;
        }
        __syncthreads();
#pragma unroll
        for (int kk = 0; kk < 64; kk += 32) {
            int ob = (kk >> 3) + quad;
            int r = w * 16 + m16;
            short8 a = *(const short8*)(As + r * 64 + sw(r, ob));
#pragma unroll
            for (int j = 0; j < 4; j++) {
                int rb = j * 16 + m16;
                short8 b = *(const short8*)(Bs + rb * 64 + sw(rb, ob));
                acc[j] = __builtin_amdgcn_mfma_f32_16x16x32_bf16(a, b, acc[j], 0, 0, 0);
            }
        }
    }
#pragma unroll
    for (int j = 0; j < 4; j++)
#pragma unroll
        for (int reg = 0; reg < 4; reg++) {
            int row = m0 + w * 16 + quad * 4 + reg;
            int col = j * 16 + m16;
            if (row < M)
                hl2q[(size_t)row * 64 + col] =
                    (unsigned char)(__builtin_amdgcn_cvt_pk_fp8_f32(acc[j][reg], 0.f, 0, false) & 0xFF);
        }
    float sa[4] = {}, sd[4] = {};
#pragma unroll
    for (int j = 0; j < 4; j++) {
        int col = j * 16 + m16;
        float as_ = a2s[col], ad_ = a2d[col];
#pragma unroll
        for (int reg = 0; reg < 4; reg++) {
            sa[reg] += acc[j][reg] * as_;
            sd[reg] += acc[j][reg] * ad_;
        }
    }
#pragma unroll
    for (int m = 1; m < 16; m <<= 1)
#pragma unroll
        for (int reg = 0; reg < 4; reg++) {
            sa[reg] += __shfl_xor(sa[reg], m, 64);
            sd[reg] += __shfl_xor(sd[reg], m, 64);
        }
    if (m16 == 0)
#pragma unroll
        for (int reg = 0; reg < 4; reg++) {
            int row = m0 + w * 16 + quad * 4 + reg;
            if (row < M) { als2[row] = sa[reg]; ald2[row] = sd[reg]; }
        }
}

// ---------- alpha2: per-node thread; ex2 (CSR order) + inv2 ----------
__global__ __launch_bounds__(256) void alpha2_k(const float* __restrict__ als2,
                                                const float* __restrict__ ald2,
                                                const int* __restrict__ offs,
                                                const int* __restrict__ csr,
                                                float* __restrict__ ex2,
                                                float* __restrict__ inv2, int N) {
    int n = blockIdx.x * blockDim.x + threadIdx.x;
    if (n >= N) return;
    float dl = ald2[n];
    int p0 = offs[n], p1 = offs[n + 1];
    float ssum = 0.f;
    for (int p = p0; p < p1; p++) {
        float xv = __expf(lrelu(als2[csr[p]] + dl));
        ex2[p] = xv;
        ssum += xv;
    }
    inv2[n] = 1.f / (ssum + 1e-16f);
}

// ---------- agg2: exp-free weighted gather over fp8 hl2 (2-edge unroll) ----------
__global__ __launch_bounds__(256) void agg2_k(const unsigned short* __restrict__ hl2q16,
                                              const float* __restrict__ ex2,
                                              const float* __restrict__ inv2,
                                              const float* __restrict__ b2,
                                              const int* __restrict__ offs,
                                              const int* __restrict__ csr,
                                              float* __restrict__ gpart, int N) {
    __shared__ float red[512];
    int slot = threadIdx.x >> 5, l = threadIdx.x & 31;
    int n = blockIdx.x * 8 + slot;
    float v0 = 0.f, v1 = 0.f;
    if (n < N) {
        int p0 = offs[n], p1 = offs[n + 1];
        float a0 = 0.f, a1 = 0.f;
        int p = p0;
        for (; p + 1 < p1; p += 2) {
            int sA = csr[p], sB = csr[p + 1];
            float xA = ex2[p], xB = ex2[p + 1];
            unsigned hA = hl2q16[sA * 32 + l];
            unsigned hB = hl2q16[sB * 32 + l];
            f32x2 fA = unpack8(hA), fB = unpack8(hB);
            a0 += xA * fA.x + xB * fB.x;
            a1 += xA * fA.y + xB * fB.y;
        }
        if (p < p1) {
            int sA = csr[p];
            float xA = ex2[p];
            f32x2 fA = unpack8(hl2q16[sA * 32 + l]);
            a0 += xA * fA.x;
            a1 += xA * fA.y;
        }
        float inv = inv2[n];
        v0 = elu(a0 * inv + b2[2 * l]);
        v1 = elu(a1 * inv + b2[2 * l + 1]);
    }
    red[slot * 64 + 2 * l] = v0;
    red[slot * 64 + 2 * l + 1] = v1;
    __syncthreads();
    if (threadIdx.x < 64) {
        float s = 0.f;
#pragma unroll
        for (int ss = 0; ss < 8; ss++) s += red[ss * 64 + threadIdx.x];
        gpart[(size_t)blockIdx.x * 64 + threadIdx.x] = s;
    }
}

// ---------- colred + final fused via last-block pattern ----------
__global__ __launch_bounds__(256) void colredfinal_k(const float* __restrict__ gpart,
                                                     float* __restrict__ gsum,
                                                     int* __restrict__ done,
                                                     const float* __restrict__ fcw,
                                                     const float* __restrict__ fcb,
                                                     float* __restrict__ out,
                                                     int NBL, int N, int NCB) {
    __shared__ float red[256];
    __shared__ int isLast;
    int t = threadIdx.x;
    int c = t & 63, rg = t >> 6;
    int bend = blockIdx.x * 256 + 256; if (bend > NBL) bend = NBL;
    float acc = 0.f;
    for (int b = blockIdx.x * 256 + rg; b < bend; b += 4)
        acc += gpart[(size_t)b * 64 + c];
    red[t] = acc;
    __syncthreads();
    if (t < 64) atomicAdd(&gsum[c], red[c] + red[c + 64] + red[c + 128] + red[c + 192]);
    __threadfence();
    if (t == 0) {
        int old = atomicAdd(done, 1);
        isLast = (old == NCB - 1) ? 1 : 0;
    }
    __syncthreads();
    if (isLast) {
        __shared__ float g[64];
        if (t < 64) g[t] = atomicAdd(&gsum[t], 0.f) / (float)N;
        __syncthreads();
        if (t < 200) {
            float a = fcb[t];
#pragma unroll
            for (int cc = 0; cc < 64; cc++) a += g[cc] * fcw[cc * 200 + t];
            out[t] = a;
        }
    }
}

extern "C" void kernel_launch(void* const* d_in, const int* in_sizes, int n_in,
                              void* d_out, int out_size, void* d_ws, size_t ws_size,
                              hipStream_t stream) {
    const int* x = (const int*)d_in[0];
    const int* ei = (const int*)d_in[1];
    const int* et = (const int*)d_in[2];
    const float* ent_emb = (const float*)d_in[3];
    const float* rel_emb = (const float*)d_in[4];
    const float* W1 = (const float*)d_in[5];
    const float* a1s = (const float*)d_in[6];
    const float* a1d = (const float*)d_in[7];
    const float* b1 = (const float*)d_in[8];
    const float* W2 = (const float*)d_in[9];
    const float* a2s = (const float*)d_in[10];
    const float* a2d = (const float*)d_in[11];
    const float* b2 = (const float*)d_in[12];
    const float* fcw = (const float*)d_in[13];
    const float* fcb = (const float*)d_in[14];
    float* out = (float*)d_out;

    int N = in_sizes[0];
    int E = in_sizes[1] / 2;
    int Etot = E + N;
    int NB = (N + 255) / 256;     // scan blocks
    int NBL = (N + 7) / 8;        // agg2 blocks
    int NCB = (NBL + 255) / 256;  // colredfinal blocks

    char* p = (char*)d_ws;
    auto alloc = [&](size_t bytes) -> char* {
        char* r = p;
        p += (bytes + 255) & ~(size_t)255;
        return r;
    };
    unsigned* h1b2 = (unsigned*)alloc((size_t)N * 64 * 4);            // bf16 pairs
    unsigned short* h1q = (unsigned short*)alloc((size_t)N * 64 * 2); // fp8 pairs (3.84 MB)
    unsigned short* wsb = (unsigned short*)alloc(2048 * 2);
    unsigned short* W1t = (unsigned short*)alloc((size_t)512 * 128 * 2);
    unsigned short* W2t = (unsigned short*)alloc((size_t)64 * 576 * 2);
    float* als1 = (float*)alloc((size_t)N * 8 * 4);
    float* ald1 = (float*)alloc((size_t)N * 8 * 4);
    unsigned short* ex1b = (unsigned short*)alloc((size_t)Etot * 8 * 2); // bf16 numerators
    float* inv1 = (float*)alloc((size_t)N * 8 * 4);
    unsigned short* Gq = (unsigned short*)alloc((size_t)N * 512 * 2); // G fp8 [N][8][128]
    unsigned char* h2q8 = (unsigned char*)alloc((size_t)N * 576);     // h2 fp8 (17.3 MB)
    unsigned char* hl2q = (unsigned char*)alloc((size_t)N * 64);      // fp8 (1.9 MB)
    float* als2 = (float*)alloc((size_t)N * 4);
    float* ald2 = (float*)alloc((size_t)N * 4);
    float* ex2  = (float*)alloc((size_t)Etot * 4);
    float* inv2 = (float*)alloc((size_t)N * 4);
    float* gpart = (float*)alloc((size_t)NBL * 64 * 4);
    int* offs   = (int*)alloc((size_t)(N + 1) * 4);
    int* csr    = (int*)alloc((size_t)Etot * 4);
    // zero-init region: deg, cursor, gsum, done, bstate (contiguous)
    char* z0 = p;
    int* deg    = (int*)alloc((size_t)N * 4);
    int* cursor = (int*)alloc((size_t)N * 4);
    float* gsum = (float*)alloc(64 * 4);
    int* done   = (int*)alloc(4);
    int* bstate = (int*)alloc((size_t)NB * 4);
    size_t zbytes = (size_t)(p - z0);

    int tb = 256;
    hipMemsetAsync(z0, 0, zbytes, stream);
    prep_k<<<(N * 64 + tb - 1) / tb, tb, 0, stream>>>(x, et, ei, ent_emb, rel_emb,
                                                      W1, W2, a1s, a1d, h1b2, h1q,
                                                      wsb, W1t, W2t, deg, N, E);
    attn1_k<<<(N + 127) / 128, 256, 0, stream>>>((const unsigned short*)h1b2, wsb, als1, ald1, N);
    scan_k<<<NB, 256, 0, stream>>>(deg, offs, bstate, N, Etot, NB);
    fill_k<<<(Etot + tb - 1) / tb, tb, 0, stream>>>(ei, E, N, offs, cursor, csr);
    alpha1_k<<<(N + 31) / 32, 256, 0, stream>>>(als1, ald1, offs, csr, ex1b, inv1, N);
    aggG_k<<<(N + 3) / 4, 256, 0, stream>>>(h1q, ex1b, inv1, offs, csr, Gq,
                                            (unsigned short*)h2q8, N);
    gemmG_k<<<dim3((N + 127) / 128, 8), 256, 0, stream>>>((const unsigned char*)Gq, W1t, b1,
                                                          h2q8, N);
    gemm2_k<<<(N + 63) / 64, 256, 0, stream>>>(h2q8, W2t, a2s, a2d, hl2q, als2, ald2, N);
    alpha2_k<<<(N + tb - 1) / tb, tb, 0, stream>>>(als2, ald2, offs, csr, ex2, inv2, N);
    agg2_k<<<NBL, 256, 0, stream>>>((const unsigned short*)hl2q, ex2, inv2, b2, offs, csr, gpart, N);
    colredfinal_k<<<NCB, 256, 0, stream>>>(gpart, gsum, done, fcw, fcb, out, NBL, N, NCB);
}

// Round 15
// 263.869 us; speedup vs baseline: 1.0073x; 1.0073x over previous
//
#include <hip/hip_runtime.h>
#include <math.h>

#define NEG_SLOPE 0.2f

typedef __attribute__((ext_vector_type(8))) short short8;   // 8 bf16 (4 VGPRs)
typedef __attribute__((ext_vector_type(4))) float f32x4;
typedef __attribute__((ext_vector_type(2))) float f32x2;

// ---------- helpers ----------
__device__ __forceinline__ float lrelu(float v) { return v > 0.f ? v : NEG_SLOPE * v; }
__device__ __forceinline__ float elu(float v) { return v > 0.f ? v : (__expf(v) - 1.f); }
__device__ __forceinline__ unsigned short f2b(float f) {   // fp32 -> bf16 RNE
    unsigned u = __float_as_uint(f);
    return (unsigned short)((u + 0x7FFFu + ((u >> 16) & 1u)) >> 16);
}
__device__ __forceinline__ float blo(unsigned v) { return __uint_as_float(v << 16); }
__device__ __forceinline__ float bhi(unsigned v) { return __uint_as_float(v & 0xFFFF0000u); }
__device__ __forceinline__ unsigned packb(float a, float b) {
    return ((unsigned)f2b(b) << 16) | (unsigned)f2b(a);
}
// fp8 e4m3 (OCP, gfx950 HW converts)
__device__ __forceinline__ unsigned short pack8(float a, float b) {
    return (unsigned short)(__builtin_amdgcn_cvt_pk_fp8_f32(a, b, 0, false) & 0xFFFF);
}
__device__ __forceinline__ f32x2 unpack8(unsigned v) {
    return __builtin_amdgcn_cvt_pk_f32_fp8((int)v, false);
}
__device__ __forceinline__ f32x2 unpack8hi(unsigned v) {
    return __builtin_amdgcn_cvt_pk_f32_fp8((int)v, true);
}
// two f32 -> packed bf16 pair by truncation (exact when inputs came from fp8)
__device__ __forceinline__ unsigned bpack_trunc(f32x2 f) {
    return (__float_as_uint(f.y) & 0xFFFF0000u) | (__float_as_uint(f.x) >> 16);
}
// LDS xor-swizzle: 16B-chunk o within row r
__device__ __forceinline__ int sw(int r, int o) { return (o ^ (r & 7)) << 3; }

// ---------- prep: h1 (bf16 + fp8) + weight transforms + degree count ----------
__global__ void prep_k(const int* __restrict__ x, const int* __restrict__ et,
                       const int* __restrict__ ei,
                       const float* __restrict__ ent_emb, const float* __restrict__ rel_emb,
                       const float* __restrict__ W1, const float* __restrict__ W2,
                       const float* __restrict__ a1s, const float* __restrict__ a1d,
                       unsigned* __restrict__ h1b2, unsigned short* __restrict__ h1q,
                       unsigned short* __restrict__ wsb, unsigned short* __restrict__ W1t,
                       unsigned short* __restrict__ W2t, int* __restrict__ deg,
                       int N, int E) {
    int t = blockIdx.x * blockDim.x + threadIdx.x;
    if (t < N * 64) {            // pair j: cols 2j, 2j+1
        int n = t >> 6, j = t & 63;
        float v0, v1;
        if (j < 32) {
            const float* e = ent_emb + (size_t)x[n] * 64 + 2 * j;
            v0 = e[0]; v1 = e[1];
        } else {
            const float* r = rel_emb + (size_t)et[n] * 64 + 2 * (j - 32);
            v0 = r[0]; v1 = r[1];
        }
        h1b2[t] = packb(v0, v1);
        h1q[t] = pack8(v0, v1);
    }
    if (t < 2048) {  // wsb[hh][k]: hh<8 -> W1.a1s, else W1.a1d
        int hh = t >> 7, k = t & 127, h = hh & 7;
        const float* aw = (hh < 8) ? a1s : a1d;
        const float* wr = W1 + (size_t)k * 512 + h * 64;
        float s_ = 0.f;
#pragma unroll 16
        for (int c = 0; c < 64; c++) s_ += wr[c] * aw[h * 64 + c];
        wsb[t] = f2b(s_);
    }
    if (t < 512 * 128) {  // W1t[n][k] = W1[k][n]
        int n = t >> 7, kk = t & 127;
        W1t[t] = f2b(W1[(size_t)kk * 512 + n]);
    }
    if (t < 64 * 576) {   // W2t[n][k] = W2[k][n]
        int n = t / 576, k = t % 576;
        W2t[t] = f2b(W2[(size_t)k * 64 + n]);
    }
    if (t < E + N) {      // degree (incl self-loop); deg[] zeroed by memset
        int dst = t < E ? ei[E + t] : t - E;
        atomicAdd(&deg[dst], 1);
    }
}

// ---------- attn1 (MFMA): [als|ald][N,16] = h1[N,128] @ wsb[16,128]^T ----------
__global__ __launch_bounds__(256) void attn1_k(const unsigned short* __restrict__ A,
                                               const unsigned short* __restrict__ Bt,
                                               float* __restrict__ als, float* __restrict__ ald,
                                               int M) {
    __shared__ __align__(16) unsigned short As[128 * 128];
    __shared__ __align__(16) unsigned short Bs[16 * 128];
    int tid = threadIdx.x;
    int m0 = blockIdx.x * 128;
    for (int c = tid; c < 2048; c += 256) {
        int r = c >> 4, o = c & 15;
        int gr = m0 + r;
        uint4 v = make_uint4(0u, 0u, 0u, 0u);
        if (gr < M) v = *(const uint4*)(A + (size_t)gr * 128 + o * 8);
        *(uint4*)(As + r * 128 + sw(r, o)) = v;
    }
    if (tid < 256) {
        int r = tid >> 4, o = tid & 15;
        uint4 v = *(const uint4*)(Bt + (size_t)r * 128 + o * 8);
        *(uint4*)(Bs + r * 128 + sw(r, o)) = v;
    }
    __syncthreads();
    int w = tid >> 6, lane = tid & 63;
    int wr = w * 32;
    int m16 = lane & 15, quad = lane >> 4;
    f32x4 acc[2] = {};
#pragma unroll
    for (int kk = 0; kk < 128; kk += 32) {
        int ob = (kk >> 3) + quad;
        short8 b = *(const short8*)(Bs + m16 * 128 + sw(m16, ob));
#pragma unroll
        for (int i = 0; i < 2; i++) {
            int r = wr + i * 16 + m16;
            short8 a = *(const short8*)(As + r * 128 + sw(r, ob));
            acc[i] = __builtin_amdgcn_mfma_f32_16x16x32_bf16(a, b, acc[i], 0, 0, 0);
        }
    }
#pragma unroll
    for (int i = 0; i < 2; i++)
#pragma unroll
        for (int reg = 0; reg < 4; reg++) {
            int row = m0 + wr + i * 16 + quad * 4 + reg;
            if (row < M) {
                if (m16 < 8) als[row * 8 + m16] = acc[i][reg];
                else         ald[row * 8 + (m16 - 8)] = acc[i][reg];
            }
        }
}

// ---------- single-dispatch decoupled-lookback scan: deg -> offs ----------
__global__ __launch_bounds__(256) void scan_k(const int* __restrict__ deg,
                                              int* __restrict__ offs,
                                              int* __restrict__ bstate,
                                              int N, int Etot, int NB) {
    __shared__ int s[256];
    __shared__ int sbase;
    int b = blockIdx.x, t = threadIdx.x;
    int i = b * 256 + t;
    int v = (i < N) ? deg[i] : 0;
    s[t] = v;
    __syncthreads();
    for (int off = 1; off < 256; off <<= 1) {
        int tmp = (t >= off) ? s[t - off] : 0;
        __syncthreads();
        s[t] += tmp;
        __syncthreads();
    }
    int total = s[255];
    if (t == 0) {
        if (b == 0) {
            atomicExch(&bstate[0], (total << 2) | 2);
            sbase = 0;
        } else {
            atomicExch(&bstate[b], (total << 2) | 1);
            int run = 0;
            for (int p = b - 1; p >= 0;) {
                int stv;
                do { stv = atomicAdd(&bstate[p], 0); } while ((stv & 3) == 0);
                run += (stv >> 2);
                if ((stv & 3) == 2) break;
                p--;
            }
            atomicExch(&bstate[b], ((run + total) << 2) | 2);
            sbase = run;
        }
    }
    __syncthreads();
    if (i < N) offs[i] = sbase + s[t] - v;
    if (b == NB - 1 && t == 0) offs[N] = Etot;
}

// ---------- CSR fill (src only) ----------
__global__ void fill_k(const int* __restrict__ ei, int E, int N,
                       const int* __restrict__ offs, int* __restrict__ cursor,
                       int* __restrict__ csr) {
    int e = blockIdx.x * blockDim.x + threadIdx.x;
    if (e >= E + N) return;
    int src = e < E ? ei[e] : e - E;
    int dst = e < E ? ei[E + e] : e - E;
    int pos = offs[dst] + atomicAdd(&cursor[dst], 1);
    csr[pos] = src;
}

// ---------- alpha1: dst-centric per-edge numerators (CSR order) + inv1 ----------
__global__ __launch_bounds__(256) void alpha1_k(const float* __restrict__ als1,
                                                const float* __restrict__ ald1,
                                                const int* __restrict__ offs,
                                                const int* __restrict__ csr,
                                                float* __restrict__ ex1,
                                                float* __restrict__ inv1, int N) {
    int slot = threadIdx.x >> 3, h = threadIdx.x & 7;
    int n = blockIdx.x * 32 + slot;
    if (n >= N) return;
    float dl = ald1[n * 8 + h];
    int p0 = offs[n], p1 = offs[n + 1];
    float ssum = 0.f;
    for (int p = p0; p < p1; p++) {
        int src = csr[p];
        float xv = __expf(lrelu(als1[src * 8 + h] + dl));
        ex1[(size_t)p * 8 + h] = xv;
        ssum += xv;
    }
    inv1[n * 8 + h] = 8.f / (ssum + 1e-16f);   // x8 fp8 scale folded in
}

// ---------- aggG: weighted gather-sum; 4-edge unroll; G fp8 x8; + h2 ent tail ----------
__global__ __launch_bounds__(256) void aggG_k(const unsigned short* __restrict__ h1q,
                                              const float* __restrict__ ex1,
                                              const float* __restrict__ inv1,
                                              const int* __restrict__ offs,
                                              const int* __restrict__ csr,
                                              unsigned short* __restrict__ Gq,
                                              unsigned short* __restrict__ h2q16, int N) {
    int wv = threadIdx.x >> 6;
    int t = threadIdx.x & 63;
    int n = blockIdx.x * 4 + wv;
    if (n >= N) return;
    int p0 = offs[n], p1 = offs[n + 1];
    float a0[8] = {}, a1[8] = {};
    int p = p0;
    for (; p + 3 < p1; p += 4) {
        int sA = csr[p], sB = csr[p + 1], sC = csr[p + 2], sD = csr[p + 3];
        float4 eA0 = *(const float4*)(ex1 + (size_t)p * 8);
        float4 eA1 = *(const float4*)(ex1 + (size_t)p * 8 + 4);
        float4 eB0 = *(const float4*)(ex1 + (size_t)p * 8 + 8);
        float4 eB1 = *(const float4*)(ex1 + (size_t)p * 8 + 12);
        float4 eC0 = *(const float4*)(ex1 + (size_t)p * 8 + 16);
        float4 eC1 = *(const float4*)(ex1 + (size_t)p * 8 + 20);
        float4 eD0 = *(const float4*)(ex1 + (size_t)p * 8 + 24);
        float4 eD1 = *(const float4*)(ex1 + (size_t)p * 8 + 28);
        unsigned hA = h1q[sA * 64 + t];
        unsigned hB = h1q[sB * 64 + t];
        unsigned hC = h1q[sC * 64 + t];
        unsigned hD = h1q[sD * 64 + t];
        f32x2 fA = unpack8(hA), fB = unpack8(hB), fC = unpack8(hC), fD = unpack8(hD);
        float evA[8] = {eA0.x, eA0.y, eA0.z, eA0.w, eA1.x, eA1.y, eA1.z, eA1.w};
        float evB[8] = {eB0.x, eB0.y, eB0.z, eB0.w, eB1.x, eB1.y, eB1.z, eB1.w};
        float evC[8] = {eC0.x, eC0.y, eC0.z, eC0.w, eC1.x, eC1.y, eC1.z, eC1.w};
        float evD[8] = {eD0.x, eD0.y, eD0.z, eD0.w, eD1.x, eD1.y, eD1.z, eD1.w};
#pragma unroll
        for (int h = 0; h < 8; h++) {
            a0[h] += evA[h] * fA.x + evB[h] * fB.x + evC[h] * fC.x + evD[h] * fD.x;
            a1[h] += evA[h] * fA.y + evB[h] * fB.y + evC[h] * fC.y + evD[h] * fD.y;
        }
    }
    for (; p < p1; p++) {
        int sA = csr[p];
        float4 eA0 = *(const float4*)(ex1 + (size_t)p * 8);
        float4 eA1 = *(const float4*)(ex1 + (size_t)p * 8 + 4);
        f32x2 fA = unpack8(h1q[sA * 64 + t]);
        float evA[8] = {eA0.x, eA0.y, eA0.z, eA0.w, eA1.x, eA1.y, eA1.z, eA1.w};
#pragma unroll
        for (int h = 0; h < 8; h++) { a0[h] += evA[h] * fA.x; a1[h] += evA[h] * fA.y; }
    }
    float4 i0 = *(const float4*)(inv1 + n * 8);
    float4 i1 = *(const float4*)(inv1 + n * 8 + 4);
    float iv[8] = {i0.x, i0.y, i0.z, i0.w, i1.x, i1.y, i1.z, i1.w};
#pragma unroll
    for (int h = 0; h < 8; h++)
        Gq[(n * 8 + h) * 64 + t] = pack8(a0[h] * iv[h], a1[h] * iv[h]);
    if (t < 32)  // ent tail: h2 fp8 cols 512..575 = h1q fp8 pairs (row stride 576B = 288 u16)
        h2q16[(size_t)n * 288 + 256 + t] = h1q[n * 64 + t];
}

// ---------- gemmG: h2(fp8) = elu((G*8)@W1t * 0.125 + b1); A staged from fp8 ----------
__global__ __launch_bounds__(256) void gemmG_k(const unsigned char* __restrict__ Gq8,
                                               const unsigned short* __restrict__ W1t,
                                               const float* __restrict__ b1,
                                               unsigned char* __restrict__ h2q8, int M) {
    __shared__ __align__(16) unsigned short As[128 * 128];
    __shared__ __align__(16) unsigned short Bs[64 * 128];
    int tid = threadIdx.x;
    int m0 = blockIdx.x * 128, h = blockIdx.y;
    for (int c = tid; c < 1024; c += 256) {
        int r = c >> 3, o = c & 7;     // o: 16-fp8 chunk
        int gr = m0 + r;
        uint4 v = make_uint4(0u, 0u, 0u, 0u);
        if (gr < M) v = *(const uint4*)(Gq8 + ((size_t)gr * 8 + h) * 128 + o * 16);
        uint4 w0, w1;
        w0.x = bpack_trunc(unpack8(v.x));   w0.y = bpack_trunc(unpack8hi(v.x));
        w0.z = bpack_trunc(unpack8(v.y));   w0.w = bpack_trunc(unpack8hi(v.y));
        w1.x = bpack_trunc(unpack8(v.z));   w1.y = bpack_trunc(unpack8hi(v.z));
        w1.z = bpack_trunc(unpack8(v.w));   w1.w = bpack_trunc(unpack8hi(v.w));
        *(uint4*)(As + r * 128 + sw(r, 2 * o)) = w0;
        *(uint4*)(As + r * 128 + sw(r, 2 * o + 1)) = w1;
    }
    for (int c = tid; c < 1024; c += 256) {
        int r = c >> 4, o = c & 15;
        uint4 v = *(const uint4*)(W1t + (size_t)(h * 64 + r) * 128 + o * 8);
        *(uint4*)(Bs + r * 128 + sw(r, o)) = v;
    }
    __syncthreads();
    int w = tid >> 6, lane = tid & 63;
    int wr = w * 32;
    int m16 = lane & 15, quad = lane >> 4;
    f32x4 acc[2][4] = {};
#pragma unroll
    for (int kk = 0; kk < 128; kk += 32) {
        int ob = (kk >> 3) + quad;
        short8 b[4];
#pragma unroll
        for (int j = 0; j < 4; j++) {
            int r = j * 16 + m16;
            b[j] = *(const short8*)(Bs + r * 128 + sw(r, ob));
        }
#pragma unroll
        for (int i = 0; i < 2; i++) {
            int r = wr + i * 16 + m16;
            short8 a = *(const short8*)(As + r * 128 + sw(r, ob));
#pragma unroll
            for (int j = 0; j < 4; j++)
                acc[i][j] = __builtin_amdgcn_mfma_f32_16x16x32_bf16(a, b[j], acc[i][j], 0, 0, 0);
        }
    }
#pragma unroll
    for (int i = 0; i < 2; i++)
#pragma unroll
        for (int j = 0; j < 4; j++)
#pragma unroll
            for (int reg = 0; reg < 4; reg++) {
                int row = m0 + wr + i * 16 + quad * 4 + reg;
                int col = h * 64 + j * 16 + m16;
                if (row < M) {
                    float v = elu(acc[i][j][reg] * 0.125f + b1[col]);
                    h2q8[(size_t)row * 576 + col] =
                        (unsigned char)(__builtin_amdgcn_cvt_pk_fp8_f32(v, 0.f, 0, false) & 0xFF);
                }
            }
}

// ---------- gemm2 (+fused attn2): hl2q(fp8) = h2(fp8) @ W2t^T ----------
__global__ __launch_bounds__(256) void gemm2_k(const unsigned char* __restrict__ Aq8,
                                               const unsigned short* __restrict__ Bt,
                                               const float* __restrict__ a2s,
                                               const float* __restrict__ a2d,
                                               unsigned char* __restrict__ hl2q,
                                               float* __restrict__ als2,
                                               float* __restrict__ ald2, int M) {
    __shared__ __align__(16) unsigned short As[64 * 64];
    __shared__ __align__(16) unsigned short Bs[64 * 64];
    int tid = threadIdx.x;
    int m0 = blockIdx.x * 64;
    int w = tid >> 6, lane = tid & 63;
    int m16 = lane & 15, quad = lane >> 4;
    f32x4 acc[4] = {};
    for (int k0 = 0; k0 < 576; k0 += 64) {
        __syncthreads();
        {   // A: 64 rows x 64 fp8 -> bf16 (exact); exactly 256 chunks
            int r = tid >> 2, o = tid & 3;   // o: 16-fp8 chunk
            int gr = m0 + r;
            uint4 v = make_uint4(0u, 0u, 0u, 0u);
            if (gr < M) v = *(const uint4*)(Aq8 + (size_t)gr * 576 + k0 + o * 16);
            uint4 w0, w1;
            w0.x = bpack_trunc(unpack8(v.x));   w0.y = bpack_trunc(unpack8hi(v.x));
            w0.z = bpack_trunc(unpack8(v.y));   w0.w = bpack_trunc(unpack8hi(v.y));
            w1.x = bpack_trunc(unpack8(v.z));   w1.y = bpack_trunc(unpack8hi(v.z));
            w1.z = bpack_trunc(unpack8(v.w));   w1.w = bpack_trunc(unpack8hi(v.w));
            *(uint4*)(As + r * 64 + sw(r, 2 * o)) = w0;
            *(uint4*)(As + r * 64 + sw(r, 2 * o + 1)) = w1;
        }
        for (int c = tid; c < 512; c += 256) {
            int r = c >> 3, o = c & 7;
            uint4 v = *(const uint4*)(Bt + (size_t)r * 576 + k0 + o * 8);
            *(uint4*)(Bs + r * 64 + sw(r, o)) = v;
        }
        __syncthreads();
#pragma unroll
        for (int kk = 0; kk < 64; kk += 32) {
            int ob = (kk >> 3) + quad;
            int r = w * 16 + m16;
            short8 a = *(const short8*)(As + r * 64 + sw(r, ob));
#pragma unroll
            for (int j = 0; j < 4; j++) {
                int rb = j * 16 + m16;
                short8 b = *(const short8*)(Bs + rb * 64 + sw(rb, ob));
                acc[j] = __builtin_amdgcn_mfma_f32_16x16x32_bf16(a, b, acc[j], 0, 0, 0);
            }
        }
    }
#pragma unroll
    for (int j = 0; j < 4; j++)
#pragma unroll
        for (int reg = 0; reg < 4; reg++) {
            int row = m0 + w * 16 + quad * 4 + reg;
            int col = j * 16 + m16;
            if (row < M)
                hl2q[(size_t)row * 64 + col] =
                    (unsigned char)(__builtin_amdgcn_cvt_pk_fp8_f32(acc[j][reg], 0.f, 0, false) & 0xFF);
        }
    float sa[4] = {}, sd[4] = {};
#pragma unroll
    for (int j = 0; j < 4; j++) {
        int col = j * 16 + m16;
        float as_ = a2s[col], ad_ = a2d[col];
#pragma unroll
        for (int reg = 0; reg < 4; reg++) {
            sa[reg] += acc[j][reg] * as_;
            sd[reg] += acc[j][reg] * ad_;
        }
    }
#pragma unroll
    for (int m = 1; m < 16; m <<= 1)
#pragma unroll
        for (int reg = 0; reg < 4; reg++) {
            sa[reg] += __shfl_xor(sa[reg], m, 64);
            sd[reg] += __shfl_xor(sd[reg], m, 64);
        }
    if (m16 == 0)
#pragma unroll
        for (int reg = 0; reg < 4; reg++) {
            int row = m0 + w * 16 + quad * 4 + reg;
            if (row < M) { als2[row] = sa[reg]; ald2[row] = sd[reg]; }
        }
}

// ---------- agg2: fused softmax+aggregate+elu over fp8 hl2 (2-edge pipeline) ----------
__global__ __launch_bounds__(256) void agg2_k(const unsigned short* __restrict__ hl2q16,
                                              const float* __restrict__ als2,
                                              const float* __restrict__ ald2,
                                              const float* __restrict__ b2,
                                              const int* __restrict__ offs,
                                              const int* __restrict__ csr,
                                              float* __restrict__ gpart, int N) {
    __shared__ float red[512];
    int slot = threadIdx.x >> 5, l = threadIdx.x & 31;
    int n = blockIdx.x * 8 + slot;
    float v0 = 0.f, v1 = 0.f;
    if (n < N) {
        float dl = ald2[n];
        int p0 = offs[n], p1 = offs[n + 1];
        float a0 = 0.f, a1 = 0.f, ssum = 0.f;
        int p = p0;
        for (; p + 1 < p1; p += 2) {
            int sA = csr[p], sB = csr[p + 1];
            float lA = als2[sA], lB = als2[sB];
            unsigned hA = hl2q16[sA * 32 + l];
            unsigned hB = hl2q16[sB * 32 + l];
            float xA = __expf(lrelu(lA + dl));
            float xB = __expf(lrelu(lB + dl));
            ssum += xA + xB;
            f32x2 fA = unpack8(hA), fB = unpack8(hB);
            a0 += xA * fA.x + xB * fB.x;
            a1 += xA * fA.y + xB * fB.y;
        }
        if (p < p1) {
            int sA = csr[p];
            float xA = __expf(lrelu(als2[sA] + dl));
            ssum += xA;
            f32x2 fA = unpack8(hl2q16[sA * 32 + l]);
            a0 += xA * fA.x;
            a1 += xA * fA.y;
        }
        float inv = 1.f / (ssum + 1e-16f);
        v0 = elu(a0 * inv + b2[2 * l]);
        v1 = elu(a1 * inv + b2[2 * l + 1]);
    }
    red[slot * 64 + 2 * l] = v0;
    red[slot * 64 + 2 * l + 1] = v1;
    __syncthreads();
    if (threadIdx.x < 64) {
        float s = 0.f;
#pragma unroll
        for (int ss = 0; ss < 8; ss++) s += red[ss * 64 + threadIdx.x];
        gpart[(size_t)blockIdx.x * 64 + threadIdx.x] = s;
    }
}

// ---------- colred + final fused via last-block pattern ----------
__global__ __launch_bounds__(256) void colredfinal_k(const float* __restrict__ gpart,
                                                     float* __restrict__ gsum,
                                                     int* __restrict__ done,
                                                     const float* __restrict__ fcw,
                                                     const float* __restrict__ fcb,
                                                     float* __restrict__ out,
                                                     int NBL, int N, int NCB) {
    __shared__ float red[256];
    __shared__ int isLast;
    int t = threadIdx.x;
    int c = t & 63, rg = t >> 6;
    int bend = blockIdx.x * 256 + 256; if (bend > NBL) bend = NBL;
    float acc = 0.f;
    for (int b = blockIdx.x * 256 + rg; b < bend; b += 4)
        acc += gpart[(size_t)b * 64 + c];
    red[t] = acc;
    __syncthreads();
    if (t < 64) atomicAdd(&gsum[c], red[c] + red[c + 64] + red[c + 128] + red[c + 192]);
    __threadfence();
    if (t == 0) {
        int old = atomicAdd(done, 1);
        isLast = (old == NCB - 1) ? 1 : 0;
    }
    __syncthreads();
    if (isLast) {
        __shared__ float g[64];
        if (t < 64) g[t] = atomicAdd(&gsum[t], 0.f) / (float)N;
        __syncthreads();
        if (t < 200) {
            float a = fcb[t];
#pragma unroll
            for (int cc = 0; cc < 64; cc++) a += g[cc] * fcw[cc * 200 + t];
            out[t] = a;
        }
    }
}

extern "C" void kernel_launch(void* const* d_in, const int* in_sizes, int n_in,
                              void* d_out, int out_size, void* d_ws, size_t ws_size,
                              hipStream_t stream) {
    const int* x = (const int*)d_in[0];
    const int* ei = (const int*)d_in[1];
    const int* et = (const int*)d_in[2];
    const float* ent_emb = (const float*)d_in[3];
    const float* rel_emb = (const float*)d_in[4];
    const float* W1 = (const float*)d_in[5];
    const float* a1s = (const float*)d_in[6];
    const float* a1d = (const float*)d_in[7];
    const float* b1 = (const float*)d_in[8];
    const float* W2 = (const float*)d_in[9];
    const float* a2s = (const float*)d_in[10];
    const float* a2d = (const float*)d_in[11];
    const float* b2 = (const float*)d_in[12];
    const float* fcw = (const float*)d_in[13];
    const float* fcb = (const float*)d_in[14];
    float* out = (float*)d_out;

    int N = in_sizes[0];
    int E = in_sizes[1] / 2;
    int Etot = E + N;
    int NB = (N + 255) / 256;     // scan blocks
    int NBL = (N + 7) / 8;        // agg2 blocks
    int NCB = (NBL + 255) / 256;  // colredfinal blocks

    char* p = (char*)d_ws;
    auto alloc = [&](size_t bytes) -> char* {
        char* r = p;
        p += (bytes + 255) & ~(size_t)255;
        return r;
    };
    unsigned* h1b2 = (unsigned*)alloc((size_t)N * 64 * 4);            // bf16 pairs
    unsigned short* h1q = (unsigned short*)alloc((size_t)N * 64 * 2); // fp8 pairs (3.84 MB)
    unsigned short* wsb = (unsigned short*)alloc(2048 * 2);
    unsigned short* W1t = (unsigned short*)alloc((size_t)512 * 128 * 2);
    unsigned short* W2t = (unsigned short*)alloc((size_t)64 * 576 * 2);
    float* als1 = (float*)alloc((size_t)N * 8 * 4);
    float* ald1 = (float*)alloc((size_t)N * 8 * 4);
    float* ex1  = (float*)alloc((size_t)Etot * 8 * 4);                // CSR-order numerators
    float* inv1 = (float*)alloc((size_t)N * 8 * 4);
    unsigned short* Gq = (unsigned short*)alloc((size_t)N * 512 * 2); // G fp8 [N][8][128]
    unsigned char* h2q8 = (unsigned char*)alloc((size_t)N * 576);     // h2 fp8 (17.3 MB)
    unsigned char* hl2q = (unsigned char*)alloc((size_t)N * 64);      // fp8 (1.9 MB)
    float* als2 = (float*)alloc((size_t)N * 4);
    float* ald2 = (float*)alloc((size_t)N * 4);
    float* gpart = (float*)alloc((size_t)NBL * 64 * 4);
    int* offs   = (int*)alloc((size_t)(N + 1) * 4);
    int* csr    = (int*)alloc((size_t)Etot * 4);
    // zero-init region: deg, cursor, gsum, done, bstate (contiguous)
    char* z0 = p;
    int* deg    = (int*)alloc((size_t)N * 4);
    int* cursor = (int*)alloc((size_t)N * 4);
    float* gsum = (float*)alloc(64 * 4);
    int* done   = (int*)alloc(4);
    int* bstate = (int*)alloc((size_t)NB * 4);
    size_t zbytes = (size_t)(p - z0);

    int tb = 256;
    hipMemsetAsync(z0, 0, zbytes, stream);
    prep_k<<<(N * 64 + tb - 1) / tb, tb, 0, stream>>>(x, et, ei, ent_emb, rel_emb,
                                                      W1, W2, a1s, a1d, h1b2, h1q,
                                                      wsb, W1t, W2t, deg, N, E);
    attn1_k<<<(N + 127) / 128, 256, 0, stream>>>((const unsigned short*)h1b2, wsb, als1, ald1, N);
    scan_k<<<NB, 256, 0, stream>>>(deg, offs, bstate, N, Etot, NB);
    fill_k<<<(Etot + tb - 1) / tb, tb, 0, stream>>>(ei, E, N, offs, cursor, csr);
    alpha1_k<<<(N + 31) / 32, 256, 0, stream>>>(als1, ald1, offs, csr, ex1, inv1, N);
    aggG_k<<<(N + 3) / 4, 256, 0, stream>>>(h1q, ex1, inv1, offs, csr, Gq,
                                            (unsigned short*)h2q8, N);
    gemmG_k<<<dim3((N + 127) / 128, 8), 256, 0, stream>>>((const unsigned char*)Gq, W1t, b1,
                                                          h2q8, N);
    gemm2_k<<<(N + 63) / 64, 256, 0, stream>>>(h2q8, W2t, a2s, a2d, hl2q, als2, ald2, N);
    agg2_k<<<NBL, 256, 0, stream>>>((const unsigned short*)hl2q, als2, ald2, b2, offs, csr, gpart, N);
    colredfinal_k<<<NCB, 256, 0, stream>>>(gpart, gsum, done, fcw, fcb, out, NBL, N, NCB);
}